// Round 14
// baseline (468.020 us; speedup 1.0000x reference)
//
#include <hip/hip_runtime.h>

using u16 = unsigned short;
typedef __attribute__((ext_vector_type(8))) short bf16x8;
typedef __attribute__((ext_vector_type(4))) float f32x4;

__device__ __forceinline__ float b2f(u16 u) { return __uint_as_float(((unsigned)u) << 16); }
__device__ __forceinline__ u16 f2b(float f) {
  unsigned x = __float_as_uint(f);
  return (u16)((x + 0x7FFFu + ((x >> 16) & 1u)) >> 16);  // RNE
}
__device__ __forceinline__ void unpack2(unsigned u, float& lo, float& hi) {
  lo = __uint_as_float(u << 16);
  hi = __uint_as_float(u & 0xFFFF0000u);
}

// ---------- static workspace ----------
__device__ __align__(16) float g_xf[786432];     // residual f32 [3072,256]
__device__ __align__(16) u16   g_xb[786432];     // bf16 copy
__device__ __align__(16) u16   g_qkv[2359296];   // [3072,768] bf16
__device__ __align__(16) u16   g_ctx[786432];    // [3072,256]; alias ff
__device__ __align__(16) u16   g_hmid[6291456];  // [3072,2048]; alias sa
__device__ __align__(16) u16   g_wb[3932160];    // bf16 weights: Wqkv|Wo|W1|W2
__device__ __align__(16) u16   g_actb[4194304];  // actions bf16
__device__ __align__(16) u16   g_wa1b[131072];   // Wa1 bf16
__device__ __align__(16) u16   g_wlabb[196608];  // Wlab bf16
__device__ __align__(16) float g_par[344584];    // small tensors f32
__device__ __align__(16) u16   g_Pab[4194304];   // Pa bf16 [16384,256]
__device__ __align__(16) u16   g_Pob[786432];    // Po bf16 [3072,256]
__device__ __align__(16) float g_sf[4194304];
__device__ __align__(16) u16   g_sfb[4194304];   // sf bf16
__device__ __align__(16) u16   g_U[12582912];    // [16384,768] bf16
__device__ float g_val[512];
__device__ float g_adv[49152];
__device__ int g_flag;

// par layout (f32 elements)
#define OFF_BQKV 0
#define OFF_BO   2304
#define OFF_B1   3072
#define OFF_B2   9216
#define OFF_LN1G 9984
#define OFF_LN1B 10752
#define OFF_LN2G 11520
#define OFF_LN2B 12288
#define OFF_BA1  144128
#define OFF_WA2  144384
#define OFF_WV   144640
#define OFF_BLAB 341504
#define OFF_BA2  341508
#define OFF_BV   341509
#define OFF_MASK 341512

#define LP 40   // padded LDS row stride (shorts): 80 B -> 2-way banks only

// ---------- dtype detect ----------
__global__ void detect_kernel(const unsigned* __restrict__ ln1_g, int* __restrict__ flag) {
  if (threadIdx.x == 0 && blockIdx.x == 0)
    *flag = (ln1_g[0] == 0x3F800000u) ? 0 : 1;
}

// ---------- fused converters ----------
struct CvtF { const void* src; float* dst; int n; };
struct CvtFJobs { CvtF e[15]; };
__global__ __launch_bounds__(256) void cvt_f32_kernel(CvtFJobs jobs, const int* flag) {
  CvtF en = jobs.e[blockIdx.y];
  int fl = *flag;
  for (int i = blockIdx.x * 256 + threadIdx.x; i < en.n; i += gridDim.x * 256)
    en.dst[i] = fl ? b2f(((const u16*)en.src)[i]) : ((const float*)en.src)[i];
}
struct CvtB { const void* src; u16* dst; int n; };
struct CvtBJobs { CvtB e[7]; };
__global__ __launch_bounds__(256) void cvt_b16_kernel(CvtBJobs jobs, const int* flag) {
  CvtB en = jobs.e[blockIdx.y];
  int fl = *flag;
  for (int i = blockIdx.x * 256 + threadIdx.x; i < en.n; i += gridDim.x * 256)
    en.dst[i] = fl ? ((const u16*)en.src)[i] : f2b(((const float*)en.src)[i]);
}

// ---------- block reduction ----------
__device__ __forceinline__ float block_sum(float v, float* red) {
  int lane = threadIdx.x & 63;
  int w = threadIdx.x >> 6;
  #pragma unroll
  for (int o = 32; o > 0; o >>= 1) v += __shfl_down(v, o, 64);
  __syncthreads();
  if (lane == 0) red[w] = v;
  __syncthreads();
  int nw = blockDim.x >> 6;
  float s = 0.f;
  for (int i = 0; i < nw; i++) s += red[i];
  return s;
}

// ---------- x = states + pos_encoding ----------
__global__ __launch_bounds__(256) void posenc_kernel(const void* __restrict__ states,
                                                     float* __restrict__ xf,
                                                     u16* __restrict__ xb,
                                                     const int* __restrict__ flag) {
  int t = blockIdx.x, e = threadIdx.x;
  int n = t % 6;
  int i = e >> 1;
  float dv = expf((float)(2 * i) * (-9.210340371976184f / 256.f));
  float ang = (float)n * dv;
  float pe = (e & 1) ? cosf(ang) : sinf(ang);
  float sv = (*flag) ? b2f(((const u16*)states)[(size_t)t * 256 + e])
                     : ((const float*)states)[(size_t)t * 256 + e];
  float v = sv + pe;
  xf[(size_t)t * 256 + e] = v;
  xb[(size_t)t * 256 + e] = f2b(v);
}

// ---------- 64x64 MFMA GEMM, BK=32, padded LDS ----------
template <typename TC, bool RELU>
__global__ __launch_bounds__(256) void mfma_gemm(const u16* __restrict__ A,
                                                 const u16* __restrict__ B,
                                                 const float* __restrict__ bias,
                                                 TC* __restrict__ C,
                                                 int K, int lda, int ldb, int ldc) {
  __shared__ __align__(16) short As[64 * LP];
  __shared__ __align__(16) short Bs[64 * LP];
  int tx = threadIdx.x;
  int row0 = blockIdx.y * 64, col0 = blockIdx.x * 64;
  int lr = tx >> 2, lc = (tx & 3) * 8;
  int lane = tx & 63, w = tx >> 6;
  int wr = (w >> 1) * 32, wc = (w & 1) * 32;
  int q = lane >> 4, mr = lane & 15;
  f32x4 acc[2][2] = {};
  const short* Ap = (const short*)A;
  const short* Bp = (const short*)B;
  for (int k0 = 0; k0 < K; k0 += 32) {
    uint4 av = *(const uint4*)(Ap + (size_t)(row0 + lr) * lda + k0 + lc);
    uint4 bv = *(const uint4*)(Bp + (size_t)(col0 + lr) * ldb + k0 + lc);
    __syncthreads();
    *(uint4*)(As + lr * LP + lc) = av;
    *(uint4*)(Bs + lr * LP + lc) = bv;
    __syncthreads();
    bf16x8 af0 = *(const bf16x8*)(As + (wr + mr) * LP + q * 8);
    bf16x8 af1 = *(const bf16x8*)(As + (wr + 16 + mr) * LP + q * 8);
    bf16x8 bf0 = *(const bf16x8*)(Bs + (wc + mr) * LP + q * 8);
    bf16x8 bf1 = *(const bf16x8*)(Bs + (wc + 16 + mr) * LP + q * 8);
    acc[0][0] = __builtin_amdgcn_mfma_f32_16x16x32_bf16(af0, bf0, acc[0][0], 0, 0, 0);
    acc[0][1] = __builtin_amdgcn_mfma_f32_16x16x32_bf16(af0, bf1, acc[0][1], 0, 0, 0);
    acc[1][0] = __builtin_amdgcn_mfma_f32_16x16x32_bf16(af1, bf0, acc[1][0], 0, 0, 0);
    acc[1][1] = __builtin_amdgcn_mfma_f32_16x16x32_bf16(af1, bf1, acc[1][1], 0, 0, 0);
  }
  #pragma unroll
  for (int j = 0; j < 2; j++) {
    int col = col0 + wc + j * 16 + mr;
    float bv_ = bias ? bias[col] : 0.f;
    #pragma unroll
    for (int i = 0; i < 2; i++) {
      #pragma unroll
      for (int r = 0; r < 4; r++) {
        int row = row0 + wr + i * 16 + q * 4 + r;
        float v = acc[i][j][r] + bv_;
        if (RELU) v = fmaxf(v, 0.f);
        if constexpr (sizeof(TC) == 4) C[(size_t)row * ldc + col] = v;
        else C[(size_t)row * ldc + col] = f2b(v);
      }
    }
  }
}

// ---------- 128x128 MFMA GEMM, BK=32, padded LDS ----------
template <typename TC, bool RELU>
__global__ __launch_bounds__(256) void mfma_gemm128(const u16* __restrict__ A,
                                                    const u16* __restrict__ B,
                                                    const float* __restrict__ bias,
                                                    TC* __restrict__ C,
                                                    int K, int lda, int ldb, int ldc) {
  __shared__ __align__(16) short As[128 * LP];
  __shared__ __align__(16) short Bs[128 * LP];
  int tx = threadIdx.x;
  int row0 = blockIdx.y * 128, col0 = blockIdx.x * 128;
  int lr = tx >> 2, lc = (tx & 3) * 8;
  int lane = tx & 63, w = tx >> 6;
  int wr = (w >> 1) * 64, wc = (w & 1) * 64;
  int q = lane >> 4, mr = lane & 15;
  f32x4 acc[4][4] = {};
  const short* Ap = (const short*)A;
  const short* Bp = (const short*)B;
  for (int k0 = 0; k0 < K; k0 += 32) {
    uint4 a0 = *(const uint4*)(Ap + (size_t)(row0 + lr) * lda + k0 + lc);
    uint4 a1 = *(const uint4*)(Ap + (size_t)(row0 + 64 + lr) * lda + k0 + lc);
    uint4 b0 = *(const uint4*)(Bp + (size_t)(col0 + lr) * ldb + k0 + lc);
    uint4 b1 = *(const uint4*)(Bp + (size_t)(col0 + 64 + lr) * ldb + k0 + lc);
    __syncthreads();
    *(uint4*)(As + lr * LP + lc) = a0;
    *(uint4*)(As + (64 + lr) * LP + lc) = a1;
    *(uint4*)(Bs + lr * LP + lc) = b0;
    *(uint4*)(Bs + (64 + lr) * LP + lc) = b1;
    __syncthreads();
    bf16x8 af[4], bf[4];
    #pragma unroll
    for (int i = 0; i < 4; i++) af[i] = *(const bf16x8*)(As + (wr + i * 16 + mr) * LP + q * 8);
    #pragma unroll
    for (int j = 0; j < 4; j++) bf[j] = *(const bf16x8*)(Bs + (wc + j * 16 + mr) * LP + q * 8);
    #pragma unroll
    for (int i = 0; i < 4; i++)
      #pragma unroll
      for (int j = 0; j < 4; j++)
        acc[i][j] = __builtin_amdgcn_mfma_f32_16x16x32_bf16(af[i], bf[j], acc[i][j], 0, 0, 0);
  }
  #pragma unroll
  for (int j = 0; j < 4; j++) {
    int col = col0 + wc + j * 16 + mr;
    float bv_ = bias ? bias[col] : 0.f;
    #pragma unroll
    for (int i = 0; i < 4; i++) {
      #pragma unroll
      for (int r = 0; r < 4; r++) {
        int row = row0 + wr + i * 16 + q * 4 + r;
        float v = acc[i][j][r] + bv_;
        if (RELU) v = fmaxf(v, 0.f);
        if constexpr (sizeof(TC) == 4) C[(size_t)row * ldc + col] = v;
        else C[(size_t)row * ldc + col] = f2b(v);
      }
    }
  }
}

// ---------- 64x64 MFMA GEMM, BK=64 (for K=2048 W2), padded LDS ----------
#define LP64 72
template <typename TC, bool RELU>
__global__ __launch_bounds__(256) void mfma_gemm_bk64(const u16* __restrict__ A,
                                                      const u16* __restrict__ B,
                                                      const float* __restrict__ bias,
                                                      TC* __restrict__ C,
                                                      int K, int lda, int ldb, int ldc) {
  __shared__ __align__(16) short As[64 * LP64];
  __shared__ __align__(16) short Bs[64 * LP64];
  int tx = threadIdx.x;
  int row0 = blockIdx.y * 64, col0 = blockIdx.x * 64;
  int lr = tx >> 2, lc = (tx & 3) * 16;
  int lane = tx & 63, w = tx >> 6;
  int wr = (w >> 1) * 32, wc = (w & 1) * 32;
  int q = lane >> 4, mr = lane & 15;
  f32x4 acc[2][2] = {};
  const short* Ap = (const short*)A;
  const short* Bp = (const short*)B;
  for (int k0 = 0; k0 < K; k0 += 64) {
    uint4 a0 = *(const uint4*)(Ap + (size_t)(row0 + lr) * lda + k0 + lc);
    uint4 a1 = *(const uint4*)(Ap + (size_t)(row0 + lr) * lda + k0 + lc + 8);
    uint4 b0 = *(const uint4*)(Bp + (size_t)(col0 + lr) * ldb + k0 + lc);
    uint4 b1 = *(const uint4*)(Bp + (size_t)(col0 + lr) * ldb + k0 + lc + 8);
    __syncthreads();
    *(uint4*)(As + lr * LP64 + lc) = a0;
    *(uint4*)(As + lr * LP64 + lc + 8) = a1;
    *(uint4*)(Bs + lr * LP64 + lc) = b0;
    *(uint4*)(Bs + lr * LP64 + lc + 8) = b1;
    __syncthreads();
    #pragma unroll
    for (int kk = 0; kk < 64; kk += 32) {
      bf16x8 af0 = *(const bf16x8*)(As + (wr + mr) * LP64 + kk + q * 8);
      bf16x8 af1 = *(const bf16x8*)(As + (wr + 16 + mr) * LP64 + kk + q * 8);
      bf16x8 bf0 = *(const bf16x8*)(Bs + (wc + mr) * LP64 + kk + q * 8);
      bf16x8 bf1 = *(const bf16x8*)(Bs + (wc + 16 + mr) * LP64 + kk + q * 8);
      acc[0][0] = __builtin_amdgcn_mfma_f32_16x16x32_bf16(af0, bf0, acc[0][0], 0, 0, 0);
      acc[0][1] = __builtin_amdgcn_mfma_f32_16x16x32_bf16(af0, bf1, acc[0][1], 0, 0, 0);
      acc[1][0] = __builtin_amdgcn_mfma_f32_16x16x32_bf16(af1, bf0, acc[1][0], 0, 0, 0);
      acc[1][1] = __builtin_amdgcn_mfma_f32_16x16x32_bf16(af1, bf1, acc[1][1], 0, 0, 0);
    }
  }
  #pragma unroll
  for (int j = 0; j < 2; j++) {
    int col = col0 + wc + j * 16 + mr;
    float bv_ = bias ? bias[col] : 0.f;
    #pragma unroll
    for (int i = 0; i < 2; i++) {
      #pragma unroll
      for (int r = 0; r < 4; r++) {
        int row = row0 + wr + i * 16 + q * 4 + r;
        float v = acc[i][j][r] + bv_;
        if (RELU) v = fmaxf(v, 0.f);
        if constexpr (sizeof(TC) == 4) C[(size_t)row * ldc + col] = v;
        else C[(size_t)row * ldc + col] = f2b(v);
      }
    }
  }
}

// ---------- MFMA flash attention ----------
__global__ __launch_bounds__(256) void attn_mfma(const u16* __restrict__ qkv,
                                                 u16* __restrict__ ctx) {
  __shared__ __align__(16) u16 VT[32 * 72];   // V^T [d][m], stride 72
  __shared__ __align__(16) u16 Ss[64 * 72];   // P [l_local][m_local], stride 72
  int tx = threadIdx.x;
  int w = tx >> 6, lane = tx & 63;
  int q = lane >> 4, mr = lane & 15;
  int nh = blockIdx.y;
  int n = nh >> 3, h = nh & 7;
  int l0 = blockIdx.x * 64;
  int lrow = l0 + w * 16 + mr;
  bf16x8 af = *(const bf16x8*)(qkv + ((size_t)lrow * 6 + n) * 768 + h * 32 + q * 8);
  const float scale = 0.17677669529663687f;
  f32x4 acc_o[2] = {};
  float dpart[4] = {0.f, 0.f, 0.f, 0.f};
  for (int mi = 0; mi < 8; mi++) {
    int m0 = mi * 64;
    __syncthreads();
    {
      int row = tx >> 2;
      int dc = (tx & 3) * 8;
      uint4 vv = *(const uint4*)(qkv + ((size_t)(m0 + row) * 6 + n) * 768 + 512 + h * 32 + dc);
      u16 tmp[8];
      *(uint4*)tmp = vv;
      #pragma unroll
      for (int i = 0; i < 8; i++) VT[(dc + i) * 72 + row] = tmp[i];
    }
    f32x4 accs[4];
    #pragma unroll
    for (int nt = 0; nt < 4; nt++) {
      bf16x8 bf = *(const bf16x8*)(qkv + ((size_t)(m0 + nt * 16 + mr) * 6 + n) * 768 +
                                   256 + h * 32 + q * 8);
      f32x4 z = {0.f, 0.f, 0.f, 0.f};
      accs[nt] = __builtin_amdgcn_mfma_f32_16x16x32_bf16(af, bf, z, 0, 0, 0);
    }
    #pragma unroll
    for (int nt = 0; nt < 4; nt++) {
      #pragma unroll
      for (int r = 0; r < 4; r++) {
        float e = __expf(fminf(accs[nt][r] * scale, 60.f));
        dpart[r] += e;
        Ss[(w * 16 + q * 4 + r) * 72 + nt * 16 + mr] = f2b(e);
      }
    }
    __syncthreads();
    #pragma unroll
    for (int dt = 0; dt < 2; dt++) {
      #pragma unroll
      for (int kc = 0; kc < 2; kc++) {
        bf16x8 ap = *(const bf16x8*)(Ss + (w * 16 + mr) * 72 + kc * 32 + q * 8);
        bf16x8 bv = *(const bf16x8*)(VT + (dt * 16 + mr) * 72 + kc * 32 + q * 8);
        acc_o[dt] = __builtin_amdgcn_mfma_f32_16x16x32_bf16(ap, bv, acc_o[dt], 0, 0, 0);
      }
    }
  }
  #pragma unroll
  for (int r = 0; r < 4; r++) {
    float d = dpart[r];
    d += __shfl_xor(d, 1, 64);
    d += __shfl_xor(d, 2, 64);
    d += __shfl_xor(d, 4, 64);
    d += __shfl_xor(d, 8, 64);
    dpart[r] = d;
  }
  #pragma unroll
  for (int dt = 0; dt < 2; dt++) {
    #pragma unroll
    for (int r = 0; r < 4; r++) {
      int l = l0 + w * 16 + q * 4 + r;
      int d = dt * 16 + mr;
      ctx[((size_t)l * 6 + n) * 256 + h * 32 + d] = f2b(acc_o[dt][r] / dpart[r]);
    }
  }
}

// ---------- x = LayerNorm(xf + addend); g,b f32 ----------
__global__ __launch_bounds__(256) void ln_kernel(float* __restrict__ xf,
                                                 u16* __restrict__ xb,
                                                 const u16* __restrict__ addend,
                                                 const float* __restrict__ g,
                                                 const float* __restrict__ b) {
  int t = blockIdx.x, e = threadIdx.x;
  __shared__ float red[4];
  float v = xf[(size_t)t * 256 + e] + b2f(addend[(size_t)t * 256 + e]);
  float mu = block_sum(v, red) * (1.f / 256.f);
  float d = v - mu;
  float var = block_sum(d * d, red) * (1.f / 256.f);
  float y = d / sqrtf(var + 1e-5f) * g[e] + b[e];
  xf[(size_t)t * 256 + e] = y;
  xb[(size_t)t * 256 + e] = f2b(y);
}

// ---------- aggregate: one wave per (b,q), barrier-free ----------
__global__ __launch_bounds__(256) void agg_kernel(const u16* __restrict__ Pa,
                                                  const u16* __restrict__ Po,
                                                  const float* __restrict__ Wa2,
                                                  const float* __restrict__ ba2,
                                                  const float* __restrict__ state_mask,
                                                  const float* __restrict__ out,
                                                  float* __restrict__ sf,
                                                  u16* __restrict__ sfb) {
  int w = threadIdx.x >> 6, lane = threadIdx.x & 63;
  int bq = blockIdx.x * 4 + w;
  int b = bq >> 5;
  int h4 = lane * 4;
  // lane's 4 h's
  uint2 pau = *(const uint2*)(Pa + (size_t)bq * 256 + h4);
  float pa0, pa1, pa2, pa3;
  unpack2(pau.x, pa0, pa1); unpack2(pau.y, pa2, pa3);
  float4 w2 = *(const float4*)(Wa2 + h4);
  float a2 = ba2[0];
  float Aw[6];
  float dsum = 0.f;
  #pragma unroll
  for (int k = 0; k < 6; k++) {
    uint2 pou = *(const uint2*)(Po + (size_t)(b * 6 + k) * 256 + h4);
    float po0, po1, po2, po3;
    unpack2(pou.x, po0, po1); unpack2(pou.y, po2, po3);
    float s = fmaxf(pa0 + po0, 0.f) * w2.x + fmaxf(pa1 + po1, 0.f) * w2.y +
              fmaxf(pa2 + po2, 0.f) * w2.z + fmaxf(pa3 + po3, 0.f) * w2.w;
    #pragma unroll
    for (int o = 1; o < 64; o <<= 1) s += __shfl_xor(s, o, 64);   // all lanes get sum
    float a = fminf(fmaxf(s + a2, 0.f), 80.f);
    float e = (state_mask[b * 6 + k] > 0.f) ? __expf(a) : 0.f;
    Aw[k] = e;
    dsum += e;
  }
  float inv = 1.f / fmaxf(dsum, 2e-15f);
  float4 acc = {0.f, 0.f, 0.f, 0.f};
  #pragma unroll
  for (int k = 0; k < 6; k++) {
    float4 ov = *(const float4*)(out + (size_t)(b * 6 + k) * 256 + h4);
    float aw = Aw[k];
    acc.x = fmaf(aw, ov.x, acc.x);
    acc.y = fmaf(aw, ov.y, acc.y);
    acc.z = fmaf(aw, ov.z, acc.z);
    acc.w = fmaf(aw, ov.w, acc.w);
  }
  acc.x *= inv; acc.y *= inv; acc.z *= inv; acc.w *= inv;
  *(float4*)(sf + (size_t)bq * 256 + h4) = acc;
  uint2 pk;
  pk.x = (unsigned)f2b(acc.x) | ((unsigned)f2b(acc.y) << 16);
  pk.y = (unsigned)f2b(acc.z) | ((unsigned)f2b(acc.w) << 16);
  *(uint2*)(sfb + (size_t)bq * 256 + h4) = pk;
}

// ---------- val ----------
__global__ __launch_bounds__(256) void val_kernel(const float* __restrict__ sf,
                                                  const float* __restrict__ Wv,
                                                  const float* __restrict__ bv,
                                                  float* __restrict__ val) {
  int b = blockIdx.x, j = threadIdx.x;
  __shared__ float red[4];
  float m = 0.f;
  for (int q = 0; q < 32; q++) m += sf[((size_t)b * 32 + q) * 256 + j];
  m *= (1.f / 32.f);
  float s = block_sum(m * Wv[j], red);
  if (j == 0) val[b] = s + bv[0];
}

// ---------- adv dot ----------
__global__ __launch_bounds__(256) void adv_dot(const u16* __restrict__ actb,
                                               const u16* __restrict__ U,
                                               const float* __restrict__ blab,
                                               float* __restrict__ adv) {
  int w = threadIdx.x >> 6, lane = threadIdx.x & 63;
  int t = blockIdx.x * 4 + w;
  uint2 av = *(const uint2*)(actb + (size_t)t * 256 + lane * 4);
  float a0, a1, a2, a3;
  unpack2(av.x, a0, a1); unpack2(av.y, a2, a3);
  #pragma unroll
  for (int l = 0; l < 3; l++) {
    uint2 uv = *(const uint2*)(U + (size_t)t * 768 + l * 256 + lane * 4);
    float u0, u1, u2, u3;
    unpack2(uv.x, u0, u1); unpack2(uv.y, u2, u3);
    float s = a0 * u0 + a1 * u1 + a2 * u2 + a3 * u3;
    #pragma unroll
    for (int o = 32; o > 0; o >>= 1) s += __shfl_down(s, o, 64);
    if (lane == 0) adv[(size_t)t * 3 + l] = s + blab[l];
  }
}

// ---------- final ----------
__global__ __launch_bounds__(128) void final_kernel(const float* __restrict__ adv,
                                                    const float* __restrict__ val,
                                                    void* __restrict__ out,
                                                    const int* __restrict__ flag) {
  int b = blockIdx.x, t = threadIdx.x;
  __shared__ float red[2];
  float v = (t < 96) ? adv[(size_t)b * 96 + t] : 0.f;
  float s = block_sum(v, red);
  float mean = s * (1.f / 96.f);
  if (t < 96) {
    float q = val[b] + v - mean;
    if (*flag) ((u16*)out)[(size_t)b * 96 + t] = f2b(q);
    else       ((float*)out)[(size_t)b * 96 + t] = q;
  }
}

extern "C" void kernel_launch(void* const* d_in, const int* in_sizes, int n_in,
                              void* d_out, int out_size, void* d_ws, size_t ws_size,
                              hipStream_t stream) {
  float *xf, *par, *sf, *val, *adv;
  u16 *xb, *qkvb, *ctxb, *hmidb, *wb, *actb, *wa1b, *wlabb, *sfb, *U, *Pab, *Pob;
  int* flag;
  hipGetSymbolAddress((void**)&xf,    HIP_SYMBOL(g_xf));
  hipGetSymbolAddress((void**)&xb,    HIP_SYMBOL(g_xb));
  hipGetSymbolAddress((void**)&qkvb,  HIP_SYMBOL(g_qkv));
  hipGetSymbolAddress((void**)&ctxb,  HIP_SYMBOL(g_ctx));
  hipGetSymbolAddress((void**)&hmidb, HIP_SYMBOL(g_hmid));
  hipGetSymbolAddress((void**)&wb,    HIP_SYMBOL(g_wb));
  hipGetSymbolAddress((void**)&actb,  HIP_SYMBOL(g_actb));
  hipGetSymbolAddress((void**)&wa1b,  HIP_SYMBOL(g_wa1b));
  hipGetSymbolAddress((void**)&wlabb, HIP_SYMBOL(g_wlabb));
  hipGetSymbolAddress((void**)&par,   HIP_SYMBOL(g_par));
  hipGetSymbolAddress((void**)&Pab,   HIP_SYMBOL(g_Pab));
  hipGetSymbolAddress((void**)&Pob,   HIP_SYMBOL(g_Pob));
  hipGetSymbolAddress((void**)&sf,    HIP_SYMBOL(g_sf));
  hipGetSymbolAddress((void**)&sfb,   HIP_SYMBOL(g_sfb));
  hipGetSymbolAddress((void**)&U,     HIP_SYMBOL(g_U));
  hipGetSymbolAddress((void**)&val,   HIP_SYMBOL(g_val));
  hipGetSymbolAddress((void**)&adv,   HIP_SYMBOL(g_adv));
  hipGetSymbolAddress((void**)&flag,  HIP_SYMBOL(g_flag));
  u16* sab = hmidb;   // [3072,256] alias during attention phase
  u16* ffb = ctxb;    // [3072,256] alias during FFN phase

  detect_kernel<<<1, 64, 0, stream>>>((const unsigned*)d_in[8], flag);

  CvtFJobs jf;
  jf.e[0]  = { d_in[5],  par + OFF_BQKV, 2304 };
  jf.e[1]  = { d_in[7],  par + OFF_BO,   768 };
  jf.e[2]  = { d_in[11], par + OFF_B1,   6144 };
  jf.e[3]  = { d_in[13], par + OFF_B2,   768 };
  jf.e[4]  = { d_in[8],  par + OFF_LN1G, 768 };
  jf.e[5]  = { d_in[9],  par + OFF_LN1B, 768 };
  jf.e[6]  = { d_in[14], par + OFF_LN2G, 768 };
  jf.e[7]  = { d_in[15], par + OFF_LN2B, 768 };
  jf.e[8]  = { d_in[17], par + OFF_BA1,  256 };
  jf.e[9]  = { d_in[18], par + OFF_WA2,  256 };
  jf.e[10] = { d_in[20], par + OFF_WV,   256 };
  jf.e[11] = { d_in[23], par + OFF_BLAB, 3 };
  jf.e[12] = { d_in[19], par + OFF_BA2,  1 };
  jf.e[13] = { d_in[21], par + OFF_BV,   1 };
  jf.e[14] = { d_in[1],  par + OFF_MASK, 3072 };
  cvt_f32_kernel<<<dim3(24, 15), 256, 0, stream>>>(jf, flag);

  CvtBJobs jb;
  jb.e[0] = { d_in[4],  wb,           589824 };   // Wqkv
  jb.e[1] = { d_in[6],  wb + 589824,  196608 };   // Wo
  jb.e[2] = { d_in[10], wb + 786432,  1572864 };  // W1
  jb.e[3] = { d_in[12], wb + 2359296, 1572864 };  // W2
  jb.e[4] = { d_in[16], wa1b,         131072 };   // Wa1
  jb.e[5] = { d_in[22], wlabb,        196608 };   // Wlab
  jb.e[6] = { d_in[2],  actb,         4194304 };  // actions
  cvt_b16_kernel<<<dim3(512, 7), 256, 0, stream>>>(jb, flag);

  posenc_kernel<<<3072, 256, 0, stream>>>(d_in[0], xf, xb, flag);

  for (int i = 0; i < 3; i++) {
    mfma_gemm128<u16, false><<<dim3(6, 24), 256, 0, stream>>>(
        xb, wb + (size_t)i * 196608, par + OFF_BQKV + i * 768, qkvb, 256, 256, 256, 768);
    attn_mfma<<<dim3(8, 48), 256, 0, stream>>>(qkvb, ctxb);
    mfma_gemm<u16, false><<<dim3(4, 48), 256, 0, stream>>>(
        ctxb, wb + 589824 + (size_t)i * 65536, par + OFF_BO + i * 256, sab, 256, 256, 256, 256);
    ln_kernel<<<3072, 256, 0, stream>>>(xf, xb, sab, par + OFF_LN1G + i * 256, par + OFF_LN1B + i * 256);
    mfma_gemm128<u16, true><<<dim3(16, 24), 256, 0, stream>>>(
        xb, wb + 786432 + (size_t)i * 524288, par + OFF_B1 + i * 2048, hmidb, 256, 256, 256, 2048);
    mfma_gemm_bk64<u16, false><<<dim3(4, 48), 256, 0, stream>>>(
        hmidb, wb + 2359296 + (size_t)i * 524288, par + OFF_B2 + i * 256, ffb, 2048, 2048, 2048, 256);
    ln_kernel<<<3072, 256, 0, stream>>>(xf, xb, ffb, par + OFF_LN2G + i * 256, par + OFF_LN2B + i * 256);
  }
  // xf holds transformer output "out" (f32), xb the bf16 copy

  mfma_gemm128<u16, false><<<dim3(2, 128), 256, 0, stream>>>(
      actb, wa1b, par + OFF_BA1, Pab, 256, 256, 512, 256);
  mfma_gemm<u16, false><<<dim3(4, 48), 256, 0, stream>>>(
      xb, wa1b + 256, nullptr, Pob, 256, 256, 512, 256);

  agg_kernel<<<4096, 256, 0, stream>>>(Pab, Pob, par + OFF_WA2, par + OFF_BA2,
                                       par + OFF_MASK, xf, sf, sfb);
  val_kernel<<<512, 256, 0, stream>>>(sf, par + OFF_WV, par + OFF_BV, val);

  mfma_gemm128<u16, false><<<dim3(6, 128), 256, 0, stream>>>(
      sfb, wlabb, nullptr, U, 256, 256, 256, 768);
  adv_dot<<<4096, 256, 0, stream>>>(actb, U, par + OFF_BLAB, adv);
  final_kernel<<<512, 128, 0, stream>>>(adv, val, d_out, flag);
}